// Round 8
// baseline (2674.888 us; speedup 1.0000x reference)
//
#include <hip/hip_runtime.h>

#define B_ 64
#define T_ 512
#define E_ 512
#define H_ 1024
#define C_ 20
#define RING 16
#define BH (B_ * H_)

typedef __attribute__((ext_vector_type(8))) _Float16 f16x8;
typedef __attribute__((ext_vector_type(4))) float f32x4;
typedef __attribute__((ext_vector_type(4))) unsigned int u32x4;
typedef unsigned long long u64;

__device__ __forceinline__ void st_agent_u64(u64* p, u64 v){
  __hip_atomic_store(p, v, __ATOMIC_RELAXED, __HIP_MEMORY_SCOPE_AGENT);
}
// Coherent 16B load (bypasses L1/L2, reads at the device-coherent point).
// Caller must s_waitcnt vmcnt(0) + sched_barrier(0) before consuming.
__device__ __forceinline__ u32x4 ld_b128_cohere(const void* p){
  u32x4 r;
  asm volatile("global_load_dwordx4 %0, %1, off sc0 sc1"
               : "=v"(r) : "v"(p) : "memory");
  return r;
}

// ---------------------------------------------------------------------------
// Prep: W_hh/W_ih -> fp16, init h-ring (slot0 = h0 = zeros, slots 1..15 =
// 0xFFFF sentinel = fp16 NaN, never produced by tanh). Ring MUST be re-inited
// every launch (ws not re-poisoned between graph replays).
// ---------------------------------------------------------------------------
__global__ void prep_kernel(const float* __restrict__ wih,
                            const float* __restrict__ whh,
                            _Float16* __restrict__ whhF,
                            _Float16* __restrict__ wihF,
                            short* __restrict__ hring)
{
  const long NH = (long)H_ * H_;
  const long NI = (long)H_ * E_;
  const long NR = (long)RING * BH;
  const long TOT = NH + NI + NR;
  long i = (long)blockIdx.x * blockDim.x + threadIdx.x;
  const long stride = (long)gridDim.x * blockDim.x;
  for (; i < TOT; i += stride){
    if (i < NH){
      whhF[i] = (_Float16)whh[i];
    } else if (i < NH + NI){
      long j = i - NH;
      wihF[j] = (_Float16)wih[j];
    } else {
      long j = i - NH - NI;
      hring[j] = (j < BH) ? (short)0 : (short)0xFFFF;
    }
  }
}

// ---------------------------------------------------------------------------
// xp_gemm: xp[t][b][h] = x[b][t][:] @ W_ih[h][:] + b_ih[h] + b_hh[h], fp16,
// stored PRE-SWIZZLED in MFMA C-fragment order so the scan reads one u64 per
// lane per col-chunk:  xp[((t*64 + cc)*4 + bg)*64 + lane]  holds the 4 f32
// C-frag elements (col = cc*16 + lane&15, rows bg*16 + (lane>>4)*4 + j).
// Grid: (T/4) x 4bg blocks, 256 thr; wave w owns cols w*256..+256, 4 t's.
// ---------------------------------------------------------------------------
__global__ __launch_bounds__(256, 1) void xp_gemm(
    const float* __restrict__ x, const _Float16* __restrict__ wihF,
    const float* __restrict__ bih, const float* __restrict__ bhh,
    u64* __restrict__ xp)
{
  const int lane = threadIdx.x & 63;
  const int wv   = threadIdx.x >> 6;       // 0..3 -> col quarter
  const int bg   = blockIdx.x & 3;
  const int tb   = (blockIdx.x >> 2) * 4;  // 4 timesteps per block
  const int r16  = lane & 15;
  const int k8   = (lane >> 4) * 8;

  const int brow = bg * 16 + r16;

  f32x4 acc[4][16];
  #pragma unroll
  for (int t = 0; t < 4; t++)
    #pragma unroll
    for (int c = 0; c < 16; c++) acc[t][c] = { 0.f, 0.f, 0.f, 0.f };

  for (int kc = 0; kc < 16; kc++){
    f16x8 a[4];
    #pragma unroll
    for (int t = 0; t < 4; t++){
      const float* xp8 = x + ((long)brow * T_ + tb + t) * E_ + kc * 32 + k8;
      float4 f0 = *(const float4*)xp8;
      float4 f1 = *(const float4*)(xp8 + 4);
      f16x8 v;
      v[0]=(_Float16)f0.x; v[1]=(_Float16)f0.y; v[2]=(_Float16)f0.z; v[3]=(_Float16)f0.w;
      v[4]=(_Float16)f1.x; v[5]=(_Float16)f1.y; v[6]=(_Float16)f1.z; v[7]=(_Float16)f1.w;
      a[t] = v;
    }
    #pragma unroll
    for (int c = 0; c < 16; c++){
      f16x8 b = *(const f16x8*)(wihF + (long)(wv * 256 + c * 16 + r16) * E_ + kc * 32 + k8);
      #pragma unroll
      for (int t = 0; t < 4; t++)
        acc[t][c] = __builtin_amdgcn_mfma_f32_16x16x32_f16(a[t], b, acc[t][c], 0, 0, 0);
    }
  }
  #pragma unroll
  for (int c = 0; c < 16; c++){
    int col = wv * 256 + c * 16 + r16;
    float bs = bih[col] + bhh[col];
    int cc = wv * 16 + c;
    #pragma unroll
    for (int t = 0; t < 4; t++){
      union { _Float16 h[4]; u64 q; } pu;
      #pragma unroll
      for (int j = 0; j < 4; j++) pu.h[j] = (_Float16)(acc[t][c][j] + bs);
      xp[(((long)(tb + t) * 64 + cc) * 4 + bg) * 64 + lane] = pu.q;
    }
  }
}

// ---------------------------------------------------------------------------
// Persistent scan v5: 128 blocks x 64 threads (one wave each, zero barriers).
// Wave (bg,cg) owns [16 batch x 32 cols], FULL K=1024: 64 recurrent MFMAs,
// W_hh pinned in 256 VGPRs. Input projection fully precomputed (xp_gemm);
// per step the wave reads 2x8B xp granules, prefetched one step ahead.
//
// Exchange: 16-slot sentinel ring (8B single-copy-atomic granules, 0xFFFF =
// fp16 NaN sentinel). Poll = 32 x 16B coherent loads (validate both 8B
// halves), arrival-order fused MFMAs. Re-sentinel slot t+8 each step; the
// per-iteration vmcnt(0) drains order its commit before any later publish.
// Fan-in: 32 producers (same bg). bg groups are fully independent systems.
// ---------------------------------------------------------------------------
__global__ __launch_bounds__(64, 1) void rnn_scan(
    const u64* __restrict__ xp, const _Float16* __restrict__ whhF,
    _Float16* __restrict__ hring, float* __restrict__ hT)
{
  const int lane = threadIdx.x;       // 0..63
  const int bg   = blockIdx.x >> 5;   // batch group 0..3
  const int cg   = blockIdx.x & 31;   // col group 0..31 (32 cols each)
  const int r16  = lane & 15;
  const int k8   = (lane >> 4) * 8;

  __shared__ float tile[16][36];      // 16 x 32 f32 transpose buffer (+4 pad)

  const int hrow = bg * 16 + r16;     // batch row (A-frag row)

  // --- pinned W_hh fragments: 2 col-chunks x 32 K-chunks ---
  f16x8 whA[32], whB[32];
  #pragma unroll
  for (int c = 0; c < 32; c++){
    whA[c] = *(const f16x8*)(whhF + (long)(cg * 32 + r16) * H_ + c * 32 + k8);
    whB[c] = *(const f16x8*)(whhF + (long)(cg * 32 + 16 + r16) * H_ + c * 32 + k8);
  }
  #pragma unroll
  for (int c = 0; c < 32; c++) asm volatile("" : "+v"(whA[c]), "+v"(whB[c]));

  const long haOff = (long)hrow * H_ + k8;          // + c*32 + slot*BH
  const int  prow  = lane >> 2;                     // publish row 0..15
  const int  pc0   = (lane & 3) * 4;                // publish col0 (of 32)
  const long pub0  = (long)(bg * 16 + prow) * H_ + cg * 32 + pc0;
  const long pub1  = pub0 + 16;
  const long xpb0  = ((long)(cg * 2 + 0) * 4 + bg) * 64 + lane;
  const long xpb1  = ((long)(cg * 2 + 1) * 4 + bg) * 64 + lane;

  // prologue: xp(0)
  u64 xc0 = xp[xpb0], xc1 = xp[xpb1];

  for (int t = 0; t < T_; ++t){
    // ---- prefetch xp(t+1) (plain cached loads; consumed next iteration) ----
    u64 xn0 = 0, xn1 = 0;
    if (t + 1 < T_){
      xn0 = xp[(long)(t + 1) * 16384 + xpb0];
      xn1 = xp[(long)(t + 1) * 16384 + xpb1];
    }

    // ---- acc init from xp(t) ----
    f32x4 accA, accB;
    {
      const _Float16* p0 = (const _Float16*)&xc0;
      const _Float16* p1 = (const _Float16*)&xc1;
      #pragma unroll
      for (int j = 0; j < 4; j++){ accA[j] = (float)p0[j]; accB[j] = (float)p1[j]; }
    }

    // ---- poll h(t): 32 x 16B coherent loads, arrival-order fused MFMAs ----
    const _Float16* hb = hring + (long)(t & (RING - 1)) * BH + haOff;
    u32x4 q[32];
    #pragma unroll
    for (int c = 0; c < 32; c++) q[c] = ld_b128_cohere(hb + c * 32);
    asm volatile("s_waitcnt vmcnt(0)" ::: "memory");
    __builtin_amdgcn_sched_barrier(0);

    unsigned need = 0xFFFFFFFFu;
    while (true){
      #pragma unroll
      for (int c = 0; c < 32; c++){
        if (need & (1u << c)){
          bool bad = ((q[c][0] & 0xFFFFu) == 0xFFFFu) ||
                     ((q[c][2] & 0xFFFFu) == 0xFFFFu);
          if (!__any(bad)){
            union { u32x4 u; f16x8 v; } hu; hu.u = q[c];
            accA = __builtin_amdgcn_mfma_f32_16x16x32_f16(hu.v, whA[c], accA, 0, 0, 0);
            accB = __builtin_amdgcn_mfma_f32_16x16x32_f16(hu.v, whB[c], accB, 0, 0, 0);
            need &= ~(1u << c);
          }
        }
      }
      if (!need) break;
      #pragma unroll
      for (int c = 0; c < 32; c++)
        if (need & (1u << c)) q[c] = ld_b128_cohere(hb + c * 32);
      asm volatile("s_waitcnt vmcnt(0)" ::: "memory");
      __builtin_amdgcn_sched_barrier(0);
    }

    // ---- tanh ----
    float hv[8];
    #pragma unroll
    for (int j = 0; j < 4; j++){
      float s = accA[j], a = fabsf(s), ex = __expf(-2.f * a);
      hv[j] = copysignf((1.f - ex) / (1.f + ex), s);
    }
    #pragma unroll
    for (int j = 0; j < 4; j++){
      float s = accB[j], a = fabsf(s), ex = __expf(-2.f * a);
      hv[4 + j] = copysignf((1.f - ex) / (1.f + ex), s);
    }

    // ---- in-wave LDS transpose: C-frag (col=r16, row=(lane>>4)*4+j) ----
    #pragma unroll
    for (int j = 0; j < 4; j++){
      tile[(lane >> 4) * 4 + j][r16]      = hv[j];
      tile[(lane >> 4) * 4 + j][16 + r16] = hv[4 + j];
    }
    f32x4 o0 = *(const f32x4*)&tile[prow][pc0];        // compiler orders DS ops
    f32x4 o1 = *(const f32x4*)&tile[prow][pc0 + 16];

    if (t < T_ - 1){
      // ---- publish 2 granules + re-sentinel slot t+8 ----
      union { _Float16 h[4]; u64 q; } g0, g1;
      #pragma unroll
      for (int j = 0; j < 4; j++){ g0.h[j] = (_Float16)o0[j]; g1.h[j] = (_Float16)o1[j]; }
      _Float16* hn = hring + (long)((t + 1) & (RING - 1)) * BH;
      st_agent_u64((u64*)(hn + pub0), g0.q);
      st_agent_u64((u64*)(hn + pub1), g1.q);
      if (t + 8 < T_){
        _Float16* hs = hring + (long)((t + 8) & (RING - 1)) * BH;
        st_agent_u64((u64*)(hs + pub0), 0xFFFFFFFFFFFFFFFFull);
        st_agent_u64((u64*)(hs + pub1), 0xFFFFFFFFFFFFFFFFull);
      }
      xc0 = xn0; xc1 = xn1;
    } else {
      *(float4*)(hT + pub0) = make_float4(o0[0], o0[1], o0[2], o0[3]);
      *(float4*)(hT + pub1) = make_float4(o1[0], o1[1], o1[2], o1[3]);
    }
  }
}

// ---------------------------------------------------------------------------
// Head: y1 = relu(hT @ fc1_w^T + b1);  out = y1 @ fc2_w^T + b2   (all fp32)
// ---------------------------------------------------------------------------
__global__ void fc1_kernel(const float* __restrict__ hT, const float* __restrict__ w1,
                           const float* __restrict__ b1, float* __restrict__ y1)
{
  int o = blockIdx.x * 256 + threadIdx.x;     // 0..65535
  int b = o >> 10, j = o & 1023;
  const float4* hp = (const float4*)(hT + (long)b * H_);
  const float4* wp = (const float4*)(w1 + (long)j * H_);
  float s = 0.f;
  #pragma unroll 4
  for (int k = 0; k < H_ / 4; k++){
    float4 hv = hp[k], wv = wp[k];
    s += hv.x * wv.x + hv.y * wv.y + hv.z * wv.z + hv.w * wv.w;
  }
  s += b1[j];
  y1[o] = s > 0.f ? s : 0.f;
}

__global__ void fc2_kernel(const float* __restrict__ y1, const float* __restrict__ w2,
                           const float* __restrict__ b2, float* __restrict__ out)
{
  __shared__ float ybuf[H_];
  int b = blockIdx.x;
  for (int k = threadIdx.x; k < H_; k += 256) ybuf[k] = y1[(long)b * H_ + k];
  __syncthreads();
  if (threadIdx.x < C_){
    const float* wp = w2 + (long)threadIdx.x * H_;
    float s = 0.f;
    for (int k = 0; k < H_; k++) s += ybuf[k] * wp[k];
    out[b * C_ + threadIdx.x] = s + b2[threadIdx.x];
  }
}

// ---------------------------------------------------------------------------
extern "C" void kernel_launch(void* const* d_in, const int* in_sizes, int n_in,
                              void* d_out, int out_size, void* d_ws, size_t ws_size,
                              hipStream_t stream)
{
  const float* x   = (const float*)d_in[0];
  const float* wih = (const float*)d_in[1];
  const float* whh = (const float*)d_in[2];
  const float* bih = (const float*)d_in[3];
  const float* bhh = (const float*)d_in[4];
  const float* w1  = (const float*)d_in[5];
  const float* b1  = (const float*)d_in[6];
  const float* w2  = (const float*)d_in[7];
  const float* b2  = (const float*)d_in[8];
  float* out = (float*)d_out;

  char* ws = (char*)d_ws;
  size_t off = 0;
  auto carve = [&](size_t bytes) -> char* {
    char* p = ws + off; off += (bytes + 255) & ~(size_t)255; return p;
  };
  _Float16* whhF  = (_Float16*)carve((size_t)H_ * H_ * 2);
  _Float16* wihF  = (_Float16*)carve((size_t)H_ * E_ * 2);
  _Float16* hring = (_Float16*)carve((size_t)RING * BH * 2);
  float*    hT    = (float*)carve((size_t)B_ * H_ * 4);
  float*    y1    = (float*)carve((size_t)B_ * H_ * 4);
  u64*      xp    = (u64*)carve((size_t)T_ * 64 * 4 * 64 * 8);   // 64 MB

  prep_kernel<<<1024, 256, 0, stream>>>(wih, whh, whhF, wihF, (short*)hring);
  xp_gemm<<<512, 256, 0, stream>>>(x, wihF, bih, bhh, xp);
  rnn_scan<<<128, 64, 0, stream>>>(xp, whhF, hring, hT);
  fc1_kernel<<<256, 256, 0, stream>>>(hT, w1, b1, y1);
  fc2_kernel<<<64, 256, 0, stream>>>(y1, w2, b2, out);
}